// Round 10
// baseline (213.074 us; speedup 1.0000x reference)
//
#include <hip/hip_runtime.h>
#include <hip/hip_bf16.h>
#include <cstdint>

#define NH   32
#define NKV  8
#define HD   64
#define CE   2048      // n_embd
#define BB   2
#define TT   2048
#define QKVD 3072      // (32 + 2*8) * 64
#define MM   (BB*TT)   // 4096 rows

typedef float  f32x4  __attribute__((ext_vector_type(4)));
typedef float  f32x16 __attribute__((ext_vector_type(16)));
typedef short  s16x8  __attribute__((ext_vector_type(8)));
typedef unsigned short u16;

#define AS1 __attribute__((address_space(1)))
#define AS3 __attribute__((address_space(3)))
#define GLDS16(src, dst) __builtin_amdgcn_global_load_lds( \
    (const AS1 uint32_t*)(src), (AS3 uint32_t*)(dst), 16, 0, 0)

static __device__ __forceinline__ float bf2f(u16 u) {
    union { uint32_t u; float f; } v; v.u = ((uint32_t)u) << 16; return v.f;
}
static __device__ __forceinline__ u16 f2bf(float f) {
    union { float f; uint32_t u; } v; v.f = f;
    uint32_t r = v.u + 0x7fffu + ((v.u >> 16) & 1u);   // RNE
    return (u16)(r >> 16);
}
static __device__ __forceinline__ uint32_t cvtpk(float lo, float hi) {
    uint32_t r;
    asm("v_cvt_pk_bf16_f32 %0, %1, %2" : "=v"(r) : "v"(lo), "v"(hi));
    return r;
}
// v_permlane32_swap_b32: a.hi32lanes <-> b.lo32lanes (both modified)
static __device__ __forceinline__ void plswap(uint32_t &a, uint32_t &b) {
    asm volatile("v_permlane32_swap_b32 %0, %1" : "+v"(a), "+v"(b));
}

// ---------------- fused converts: x/Wqkv/Wproj f32->bf16 + cs zip ----------------
static __device__ __forceinline__ void cvt8(const float* __restrict__ in, uint32_t* __restrict__ out) {
    const float4* p = reinterpret_cast<const float4*>(in);
    float4 a = p[0], b = p[1];
    uint4 o;
    o.x = cvtpk(a.x, a.y); o.y = cvtpk(a.z, a.w);
    o.z = cvtpk(b.x, b.y); o.w = cvtpk(b.z, b.w);
    *reinterpret_cast<uint4*>(out) = o;
}
__global__ void k_cvt_all(const float* __restrict__ x, const float* __restrict__ wqkv,
                          const float* __restrict__ wproj,
                          uint32_t* __restrict__ xo, uint32_t* __restrict__ wqo,
                          uint32_t* __restrict__ wpo,
                          const float* __restrict__ fcos, const float* __restrict__ fsin,
                          float2* __restrict__ csT) {
    const int n1 = MM * CE / 8, n2 = QKVD * CE / 8, n3 = CE * CE / 8, n4 = 32 * TT / 8;
    int i = blockIdx.x * blockDim.x + threadIdx.x;
    if (i < n1) {
        cvt8(x + (size_t)i * 8, xo + (size_t)i * 4);
    } else if (i < n1 + n2) {
        int k = i - n1;
        cvt8(wqkv + (size_t)k * 8, wqo + (size_t)k * 4);
    } else if (i < n1 + n2 + n3) {
        int k = i - n1 - n2;
        cvt8(wproj + (size_t)k * 8, wpo + (size_t)k * 4);
    } else if (i < n1 + n2 + n3 + n4) {
        int k = (i - n1 - n2 - n3) * 8;
        #pragma unroll
        for (int jj = 0; jj < 8; ++jj) {
            float2 cs; cs.x = fcos[k + jj]; cs.y = fsin[k + jj];
            csT[k + jj] = cs;                 // csT[t*32 + d2]
        }
    }
}

// ============ QKV GEMM, BK=64, swizzled LDS, fused RoPE + scatter epilogue ============
__global__ __launch_bounds__(256) void k_gemm_qkv(const u16* __restrict__ A,
                                                  const u16* __restrict__ Bm,
                                                  u16* __restrict__ Qb,
                                                  u16* __restrict__ Kb,
                                                  u16* __restrict__ Vt,
                                                  const float2* __restrict__ csT) {
    __shared__ u16 As[128 * 64];   // [128 rows][64 k] swizzled, 16KB
    __shared__ u16 Bs[128 * 64];
    const int K = CE;
    // XCD swizzle: 768 wgs, q=96 per XCD chunk
    const int c  = blockIdx.x + 24 * blockIdx.y;
    const int nc = (c & 7) * 96 + (c >> 3);
    const int m0 = (nc / 24) * 128;
    const int n0 = (nc % 24) * 128;

    const int tid  = threadIdx.x;
    const int w    = tid >> 6;
    const int lane = tid & 63;
    const int lr   = lane & 15, lg = lane >> 4;
    const int wm   = (w >> 1) * 64, wn = (w & 1) * 64;

    // staging: 4 shots of 4KB per matrix; thread covers rows s*32 + (tid>>3)
    const int rr = tid >> 3;               // 0..31
    const int cc = (tid & 7) * 16;         // col byte 0..112
    const int csw = cc ^ ((rr & 7) << 4);  // pre-swizzled source col byte
    size_t aof[4], bof[4];
    #pragma unroll
    for (int s = 0; s < 4; ++s) {
        const int r = s * 32 + rr;
        aof[s] = (size_t)(m0 + r) * K + (csw >> 1);
        bof[s] = (size_t)(n0 + r) * K + (csw >> 1);
    }

    f32x4 acc[4][4] = {};

    for (int k0 = 0; k0 < K; k0 += 64) {
        #pragma unroll
        for (int s = 0; s < 4; ++s)
            GLDS16(A + aof[s] + k0, (u16*)((char*)As + s * 4096 + tid * 16));
        #pragma unroll
        for (int s = 0; s < 4; ++s)
            GLDS16(Bm + bof[s] + k0, (u16*)((char*)Bs + s * 4096 + tid * 16));
        __syncthreads();
        s16x8 af[4][2], bf[4][2];
        #pragma unroll
        for (int i = 0; i < 4; ++i) {
            const int ra = wm + i * 16 + lr;
            const int x = (ra & 7) << 4;
            af[i][0] = *reinterpret_cast<const s16x8*>((const char*)As + ra * 128 + ((lg * 16) ^ x));
            af[i][1] = *reinterpret_cast<const s16x8*>((const char*)As + ra * 128 + ((64 + lg * 16) ^ x));
        }
        #pragma unroll
        for (int j = 0; j < 4; ++j) {
            const int rb = wn + j * 16 + lr;
            const int x = (rb & 7) << 4;
            bf[j][0] = *reinterpret_cast<const s16x8*>((const char*)Bs + rb * 128 + ((lg * 16) ^ x));
            bf[j][1] = *reinterpret_cast<const s16x8*>((const char*)Bs + rb * 128 + ((64 + lg * 16) ^ x));
        }
        #pragma unroll
        for (int kk = 0; kk < 2; ++kk)
            #pragma unroll
            for (int i = 0; i < 4; ++i)
                #pragma unroll
                for (int j = 0; j < 4; ++j)
                    acc[i][j] = __builtin_amdgcn_mfma_f32_16x16x32_bf16(af[i][kk], bf[j][kk], acc[i][j], 0, 0, 0);
        __syncthreads();
    }

    // fused epilogue: RoPE on packed bf16 pairs (4 shfls per fragment)
    const float QS = 0.18033688011112042f;   // (1/sqrt(64)) * log2(e)
    const int bb = m0 / TT;
    const int tb = m0 - bb * TT + wm;
    if (n0 < (NH + NKV) * HD) {              // ---- Q or K (block-uniform) ----
        const bool isq = (n0 < NH * HD);
        const bool odd = lr & 1;
        #pragma unroll
        for (int i = 0; i < 4; ++i) {
            const int t0 = tb + i * 16 + lg * 4;
            #pragma unroll
            for (int j = 0; j < 4; ++j) {
                const int n = n0 + wn + j * 16 + lr;
                const int d = n & 63;
                uint32_t m01 = cvtpk(acc[i][j][0], acc[i][j][1]);
                uint32_t m23 = cvtpk(acc[i][j][2], acc[i][j][3]);
                uint32_t p01 = __shfl_xor(m01, 1, 64);
                uint32_t p23 = __shfl_xor(m23, 1, 64);
                float o_[4];
                #pragma unroll
                for (int r = 0; r < 4; ++r) {
                    uint32_t mo = (r < 2) ? m01 : m23;
                    uint32_t po = (r < 2) ? p01 : p23;
                    u16 own = (r & 1) ? (u16)(mo >> 16) : (u16)(mo & 0xffff);
                    u16 par = (r & 1) ? (u16)(po >> 16) : (u16)(po & 0xffff);
                    float x0 = bf2f(odd ? par : own);
                    float x1 = bf2f(odd ? own : par);
                    const float2 cs2 = csT[(t0 + r) * 32 + (d >> 1)];
                    float o = odd ? (x0 * cs2.y + x1 * cs2.x) : (x0 * cs2.x - x1 * cs2.y);
                    o_[r] = isq ? o * QS : o;
                }
                uint32_t o01 = cvtpk(o_[0], o_[1]);
                uint32_t o23 = cvtpk(o_[2], o_[3]);
                uint32_t q01 = __shfl_xor(o01, 1, 64);
                uint32_t q23 = __shfl_xor(o23, 1, 64);
                if (!odd) {
                    const int hh = isq ? (n >> 6) : ((n - NH * HD) >> 6);
                    u16* base = isq ? (Qb + ((size_t)(bb * NH + hh) * TT + t0) * HD + d)
                                    : (Kb + ((size_t)(bb * NKV + hh) * TT + t0) * HD + d);
                    *reinterpret_cast<uint32_t*>(base + 0 * HD) = (o01 & 0xffffu) | (q01 << 16);
                    *reinterpret_cast<uint32_t*>(base + 1 * HD) = (o01 >> 16) | (q01 & 0xffff0000u);
                    *reinterpret_cast<uint32_t*>(base + 2 * HD) = (o23 & 0xffffu) | (q23 << 16);
                    *reinterpret_cast<uint32_t*>(base + 3 * HD) = (o23 >> 16) | (q23 & 0xffff0000u);
                }
            }
        }
    } else {                                  // ---- V: transpose store ----
        #pragma unroll
        for (int i = 0; i < 4; ++i) {
            const int t0 = tb + i * 16 + lg * 4;
            #pragma unroll
            for (int j = 0; j < 4; ++j) {
                const int n = n0 + wn + j * 16 + lr;
                const int fv = n - (NH + NKV) * HD;
                const int vh = fv >> 6, d = fv & 63;
                uint2 st;
                st.x = cvtpk(acc[i][j][0], acc[i][j][1]);
                st.y = cvtpk(acc[i][j][2], acc[i][j][3]);
                *reinterpret_cast<uint2*>(Vt + ((size_t)(bb * NKV + vh) * HD + d) * TT + t0) = st;
            }
        }
    }
}

// ---------------- bf16 GEMM, BK=64, swizzled LDS, f32 out (proj) ----------------
__global__ __launch_bounds__(256) void k_gemm_bt(const u16* __restrict__ A,
                                                 const u16* __restrict__ Bm,
                                                 float* __restrict__ Cout,
                                                 int M, int N, int K) {
    __shared__ u16 As[128 * 64];
    __shared__ u16 Bs[128 * 64];
    // XCD swizzle: 512 wgs, q=64 per XCD chunk
    const int c  = blockIdx.x + 16 * blockIdx.y;
    const int nc = (c & 7) * 64 + (c >> 3);
    const int m0 = (nc >> 4) * 128;
    const int n0 = (nc & 15) * 128;

    const int tid  = threadIdx.x;
    const int w    = tid >> 6;
    const int lane = tid & 63;
    const int lr   = lane & 15, lg = lane >> 4;
    const int wm   = (w >> 1) * 64, wn = (w & 1) * 64;

    const int rr = tid >> 3;
    const int cc = (tid & 7) * 16;
    const int csw = cc ^ ((rr & 7) << 4);
    size_t aof[4], bof[4];
    #pragma unroll
    for (int s = 0; s < 4; ++s) {
        const int r = s * 32 + rr;
        aof[s] = (size_t)(m0 + r) * K + (csw >> 1);
        bof[s] = (size_t)(n0 + r) * K + (csw >> 1);
    }

    f32x4 acc[4][4] = {};

    for (int k0 = 0; k0 < K; k0 += 64) {
        #pragma unroll
        for (int s = 0; s < 4; ++s)
            GLDS16(A + aof[s] + k0, (u16*)((char*)As + s * 4096 + tid * 16));
        #pragma unroll
        for (int s = 0; s < 4; ++s)
            GLDS16(Bm + bof[s] + k0, (u16*)((char*)Bs + s * 4096 + tid * 16));
        __syncthreads();
        s16x8 af[4][2], bf[4][2];
        #pragma unroll
        for (int i = 0; i < 4; ++i) {
            const int ra = wm + i * 16 + lr;
            const int x = (ra & 7) << 4;
            af[i][0] = *reinterpret_cast<const s16x8*>((const char*)As + ra * 128 + ((lg * 16) ^ x));
            af[i][1] = *reinterpret_cast<const s16x8*>((const char*)As + ra * 128 + ((64 + lg * 16) ^ x));
        }
        #pragma unroll
        for (int j = 0; j < 4; ++j) {
            const int rb = wn + j * 16 + lr;
            const int x = (rb & 7) << 4;
            bf[j][0] = *reinterpret_cast<const s16x8*>((const char*)Bs + rb * 128 + ((lg * 16) ^ x));
            bf[j][1] = *reinterpret_cast<const s16x8*>((const char*)Bs + rb * 128 + ((64 + lg * 16) ^ x));
        }
        #pragma unroll
        for (int kk = 0; kk < 2; ++kk)
            #pragma unroll
            for (int i = 0; i < 4; ++i)
                #pragma unroll
                for (int j = 0; j < 4; ++j)
                    acc[i][j] = __builtin_amdgcn_mfma_f32_16x16x32_bf16(af[i][kk], bf[j][kk], acc[i][j], 0, 0, 0);
        __syncthreads();
    }

    #pragma unroll
    for (int i = 0; i < 4; ++i)
        #pragma unroll
        for (int j = 0; j < 4; ++j)
            #pragma unroll
            for (int r = 0; r < 4; ++r) {
                int m = m0 + wm + i * 16 + lg * 4 + r;
                int n = n0 + wn + j * 16 + lr;
                __builtin_nontemporal_store(acc[i][j][r], &Cout[(size_t)m * N + n]);
            }
}

// ---------------- causal GQA flash attention: 8-wave shared-KV, ADJACENT pairs ----
// (unchanged from R9 — verified passing)
__global__ __launch_bounds__(512) void k_attn(const u16* __restrict__ Q,
                                              const u16* __restrict__ Kb,
                                              const u16* __restrict__ Vt,
                                              u16* __restrict__ Y) {
    __shared__ u16 Ks[2][4096];      // [kv 64][d 64] swizzled (8KB per buf)
    __shared__ u16 Vs[2][4096];      // [d 64][kv 64] swizzled

    const int tid = threadIdx.x;
    const int w = tid >> 6, lane = tid & 63;
    const int wv = w & 3, half = w >> 2;
    const int ql = lane & 31, hi = lane >> 5;
    const int hi16 = hi << 4;
    const int b = blockIdx.z, h = blockIdx.y, kvh = h >> 2;
    const int u = blockIdx.x;

    const int m  = b ? (7 - u) : u;
    const int j1 = 2 * m + 1, j2 = 2 * m;
    const int jq = half ? j2 : j1;
    const int q0w  = jq * 128 + wv * 32;
    const int nt   = 2 * j1 + 2;         // block loop length (= 4m+4)
    const int tmxw = (q0w + 31) >> 6;    // wave's diagonal tile index
    const int qabs = q0w + ql;           // this lane's q row

    const u16* qbase = Q  + ((size_t)(b * NH  + h  ) * TT) * HD;
    const u16* kbase = Kb + ((size_t)(b * NKV + kvh) * TT) * HD;
    const u16* vbase = Vt + ((size_t)(b * NKV + kvh) * HD) * TT;

    const int o0 = w * 1024 + lane * 16;
    const int r0 = o0 >> 7;
    const int c0 = (o0 & 127) ^ ((r0 & 7) << 4);
    const size_t kof0 = (size_t)r0 * HD + (c0 >> 1);
    const size_t vof0 = (size_t)r0 * TT + (c0 >> 1);

    const char* KsB = (const char*)&Ks[0][0];
    const char* VsB = (const char*)&Vs[0][0];
    const int krb0 = (0 * 32 + ql) * 128, ksz0 = ((0 * 32 + ql) & 7) << 4;
    const int krb1 = (1 * 32 + ql) * 128, ksz1 = ((1 * 32 + ql) & 7) << 4;

    s16x8 qf[4];
    #pragma unroll
    for (int ds = 0; ds < 4; ++ds)
        qf[ds] = *reinterpret_cast<const s16x8*>(qbase + (size_t)qabs * HD + ds * 16 + 8 * hi);
    asm volatile("s_waitcnt vmcnt(0)" ::: "memory");

    GLDS16(kbase + kof0, &Ks[0][w * 512]);
    GLDS16(vbase + vof0, &Vs[0][w * 512]);

    float mrow = -1e30f, lrowp = 0.f;
    f32x16 oT0 = {}, oT1 = {};

    for (int t = 0; t < nt; ++t) {
        const int cur = t & 1;
        const int kv0 = t * 64;
        if (t + 1 < nt) {
            GLDS16(kbase + (size_t)(kv0 + 64) * HD + kof0, &Ks[cur ^ 1][w * 512]);
            GLDS16(vbase + (kv0 + 64) + vof0, &Vs[cur ^ 1][w * 512]);
            asm volatile("s_waitcnt vmcnt(2)" ::: "memory");
        } else {
            asm volatile("s_waitcnt vmcnt(0)" ::: "memory");
        }
        __builtin_amdgcn_s_barrier();
        __builtin_amdgcn_sched_barrier(0);

        if (t <= tmxw) {
            const int bufo = cur * 8192;

            f32x16 sc0 = {}, sc1 = {};
            __builtin_amdgcn_s_setprio(1);
            #pragma unroll
            for (int ds = 0; ds < 4; ++ds) {
                s16x8 k0 = *reinterpret_cast<const s16x8*>(KsB + bufo + krb0 + (((ds << 5) | hi16) ^ ksz0));
                s16x8 k1 = *reinterpret_cast<const s16x8*>(KsB + bufo + krb1 + (((ds << 5) | hi16) ^ ksz1));
                sc0 = __builtin_amdgcn_mfma_f32_32x32x16_bf16(k0, qf[ds], sc0, 0, 0, 0);
                sc1 = __builtin_amdgcn_mfma_f32_32x32x16_bf16(k1, qf[ds], sc1, 0, 0, 0);
            }
            __builtin_amdgcn_s_setprio(0);

            float p0[16], p1[16];
            #pragma unroll
            for (int r = 0; r < 16; ++r) { p0[r] = sc0[r]; p1[r] = sc1[r]; }

            if (t == tmxw) {
                const int dq = qabs - kv0 - 4 * hi;
                #pragma unroll
                for (int r = 0; r < 16; ++r) {
                    const int kr = (r & 3) + 8 * (r >> 2);
                    p0[r] = (kr      <= dq) ? p0[r] : -1e30f;
                    p1[r] = (kr + 32 <= dq) ? p1[r] : -1e30f;
                }
            }

            float tmax = fmaxf(p0[0], p1[0]);
            #pragma unroll
            for (int r = 1; r < 16; ++r) tmax = fmaxf(fmaxf(tmax, p0[r]), p1[r]);
            if (__any(tmax > mrow + 8.f)) {
                float tf = fmaxf(tmax, __shfl_xor(tmax, 32, 64));
                float mn = fmaxf(mrow, tf);
                float alpha = __builtin_amdgcn_exp2f(mrow - mn);
                mrow = mn;
                lrowp *= alpha;
                #pragma unroll
                for (int r = 0; r < 16; ++r) { oT0[r] *= alpha; oT1[r] *= alpha; }
            }

            float sum = 0.f;
            #pragma unroll
            for (int r = 0; r < 16; ++r) {
                p0[r] = __builtin_amdgcn_exp2f(p0[r] - mrow);
                p1[r] = __builtin_amdgcn_exp2f(p1[r] - mrow);
                sum += p0[r] + p1[r];
            }
            lrowp += sum;

            __builtin_amdgcn_s_setprio(1);
            #pragma unroll
            for (int ks = 0; ks < 2; ++ks) {
                uint32_t a0 = cvtpk(p0[ks * 8 + 0], p0[ks * 8 + 1]);
                uint32_t b0 = cvtpk(p0[ks * 8 + 4], p0[ks * 8 + 5]);
                plswap(a0, b0);
                uint32_t a1 = cvtpk(p0[ks * 8 + 2], p0[ks * 8 + 3]);
                uint32_t b1 = cvtpk(p0[ks * 8 + 6], p0[ks * 8 + 7]);
                plswap(a1, b1);
                union { uint32_t d[4]; s16x8 v; } pb;
                pb.d[0] = a0; pb.d[1] = a1; pb.d[2] = b0; pb.d[3] = b1;
                const int colb = (0 << 6) | (ks << 5) | hi16;
                s16x8 v0 = *reinterpret_cast<const s16x8*>(VsB + bufo + krb0 + (colb ^ ksz0));
                s16x8 v1 = *reinterpret_cast<const s16x8*>(VsB + bufo + krb1 + (colb ^ ksz1));
                oT0 = __builtin_amdgcn_mfma_f32_32x32x16_bf16(v0, pb.v, oT0, 0, 0, 0);
                oT1 = __builtin_amdgcn_mfma_f32_32x32x16_bf16(v1, pb.v, oT1, 0, 0, 0);
            }
            #pragma unroll
            for (int ks = 0; ks < 2; ++ks) {
                uint32_t a0 = cvtpk(p1[ks * 8 + 0], p1[ks * 8 + 1]);
                uint32_t b0 = cvtpk(p1[ks * 8 + 4], p1[ks * 8 + 5]);
                plswap(a0, b0);
                uint32_t a1 = cvtpk(p1[ks * 8 + 2], p1[ks * 8 + 3]);
                uint32_t b1 = cvtpk(p1[ks * 8 + 6], p1[ks * 8 + 7]);
                plswap(a1, b1);
                union { uint32_t d[4]; s16x8 v; } pb;
                pb.d[0] = a0; pb.d[1] = a1; pb.d[2] = b0; pb.d[3] = b1;
                const int colb = (1 << 6) | (ks << 5) | hi16;
                s16x8 v0 = *reinterpret_cast<const s16x8*>(VsB + bufo + krb0 + (colb ^ ksz0));
                s16x8 v1 = *reinterpret_cast<const s16x8*>(VsB + bufo + krb1 + (colb ^ ksz1));
                oT0 = __builtin_amdgcn_mfma_f32_32x32x16_bf16(v0, pb.v, oT0, 0, 0, 0);
                oT1 = __builtin_amdgcn_mfma_f32_32x32x16_bf16(v1, pb.v, oT1, 0, 0, 0);
            }
            __builtin_amdgcn_s_setprio(0);
        }

        __builtin_amdgcn_sched_barrier(0);
        __builtin_amdgcn_s_barrier();
    }

    lrowp += __shfl_xor(lrowp, 32, 64);
    const float rinv = 1.f / lrowp;
    const size_t yrow = ((size_t)(b * TT + qabs) * NH + h) * HD;
    #pragma unroll
    for (int rp = 0; rp < 8; ++rp) {
        const int d = ((2 * rp) & 3) + 8 * (rp >> 1) + 4 * hi;
        *reinterpret_cast<uint32_t*>(Y + yrow + d) =
            cvtpk(oT0[2 * rp] * rinv, oT0[2 * rp + 1] * rinv);
        *reinterpret_cast<uint32_t*>(Y + yrow + 32 + d) =
            cvtpk(oT1[2 * rp] * rinv, oT1[2 * rp + 1] * rinv);
    }
}

// ---------------- launch ----------------
extern "C" void kernel_launch(void* const* d_in, const int* in_sizes, int n_in,
                              void* d_out, int out_size, void* d_ws, size_t ws_size,
                              hipStream_t stream) {
    (void)in_sizes; (void)n_in; (void)out_size; (void)ws_size;
    const float* x     = (const float*)d_in[0];
    const float* wqkv  = (const float*)d_in[1];
    const float* wproj = (const float*)d_in[2];
    const float* fcos  = (const float*)d_in[3];
    const float* fsin  = (const float*)d_in[4];

    char* ws = (char*)d_ws;
    size_t off = 0;
    auto alloc = [&](size_t bytes) { void* p = ws + off; off += (bytes + 255) & ~(size_t)255; return p; };
    u16*    Xbf  = (u16*)alloc((size_t)MM * CE * 2);
    u16*    Wqb  = (u16*)alloc((size_t)QKVD * CE * 2);
    u16*    Wpb  = (u16*)alloc((size_t)CE * CE * 2);
    u16*    Qb   = (u16*)alloc((size_t)BB * NH * TT * HD * 2);
    u16*    Kbuf = (u16*)alloc((size_t)BB * NKV * TT * HD * 2);
    u16*    Vtb  = (u16*)alloc((size_t)BB * NKV * HD * TT * 2);
    u16*    Yb   = (u16*)alloc((size_t)MM * CE * 2);
    float2* csT  = (float2*)alloc((size_t)32 * TT * sizeof(float2));

    const int ncvt = MM * CE / 8 + QKVD * CE / 8 + CE * CE / 8 + 32 * TT / 8;
    k_cvt_all<<<(ncvt + 255) / 256, 256, 0, stream>>>(x, wqkv, wproj,
                                                      (uint32_t*)Xbf, (uint32_t*)Wqb, (uint32_t*)Wpb,
                                                      fcos, fsin, csT);

    dim3 g1(QKVD / 128, MM / 128);
    k_gemm_qkv<<<g1, 256, 0, stream>>>(Xbf, Wqb, Qb, Kbuf, Vtb, csT);

    dim3 ga(8, NH, BB);
    k_attn<<<ga, 512, 0, stream>>>(Qb, Kbuf, Vtb, Yb);

    dim3 g2(CE / 128, MM / 128);
    k_gemm_bt<<<g2, 256, 0, stream>>>(Yb, Wpb, (float*)d_out, MM, CE, CE);
}

// Round 11
// 204.245 us; speedup vs baseline: 1.0432x; 1.0432x over previous
//
#include <hip/hip_runtime.h>
#include <hip/hip_bf16.h>
#include <cstdint>

#define NH   32
#define NKV  8
#define HD   64
#define CE   2048      // n_embd
#define BB   2
#define TT   2048
#define QKVD 3072      // (32 + 2*8) * 64
#define MM   (BB*TT)   // 4096 rows

typedef float  f32x4  __attribute__((ext_vector_type(4)));
typedef float  f32x16 __attribute__((ext_vector_type(16)));
typedef short  s16x8  __attribute__((ext_vector_type(8)));
typedef unsigned short u16;

#define AS1 __attribute__((address_space(1)))
#define AS3 __attribute__((address_space(3)))
#define GLDS16(src, dst) __builtin_amdgcn_global_load_lds( \
    (const AS1 uint32_t*)(src), (AS3 uint32_t*)(dst), 16, 0, 0)

static __device__ __forceinline__ float bf2f(u16 u) {
    union { uint32_t u; float f; } v; v.u = ((uint32_t)u) << 16; return v.f;
}
static __device__ __forceinline__ u16 f2bf(float f) {
    union { float f; uint32_t u; } v; v.f = f;
    uint32_t r = v.u + 0x7fffu + ((v.u >> 16) & 1u);   // RNE
    return (u16)(r >> 16);
}
static __device__ __forceinline__ uint32_t cvtpk(float lo, float hi) {
    uint32_t r;
    asm("v_cvt_pk_bf16_f32 %0, %1, %2" : "=v"(r) : "v"(lo), "v"(hi));
    return r;
}
// v_permlane32_swap_b32: a.hi32lanes <-> b.lo32lanes (both modified)
static __device__ __forceinline__ void plswap(uint32_t &a, uint32_t &b) {
    asm volatile("v_permlane32_swap_b32 %0, %1" : "+v"(a), "+v"(b));
}

// ---------------- fused converts: x/Wqkv/Wproj f32->bf16 + cs zip ----------------
static __device__ __forceinline__ void cvt8(const float* __restrict__ in, uint32_t* __restrict__ out) {
    const float4* p = reinterpret_cast<const float4*>(in);
    float4 a = p[0], b = p[1];
    uint4 o;
    o.x = cvtpk(a.x, a.y); o.y = cvtpk(a.z, a.w);
    o.z = cvtpk(b.x, b.y); o.w = cvtpk(b.z, b.w);
    *reinterpret_cast<uint4*>(out) = o;
}
__global__ void k_cvt_all(const float* __restrict__ x, const float* __restrict__ wqkv,
                          const float* __restrict__ wproj,
                          uint32_t* __restrict__ xo, uint32_t* __restrict__ wqo,
                          uint32_t* __restrict__ wpo,
                          const float* __restrict__ fcos, const float* __restrict__ fsin,
                          float2* __restrict__ csT) {
    const int n1 = MM * CE / 8, n2 = QKVD * CE / 8, n3 = CE * CE / 8, n4 = 32 * TT / 8;
    int i = blockIdx.x * blockDim.x + threadIdx.x;
    if (i < n1) {
        cvt8(x + (size_t)i * 8, xo + (size_t)i * 4);
    } else if (i < n1 + n2) {
        int k = i - n1;
        cvt8(wqkv + (size_t)k * 8, wqo + (size_t)k * 4);
    } else if (i < n1 + n2 + n3) {
        int k = i - n1 - n2;
        cvt8(wproj + (size_t)k * 8, wpo + (size_t)k * 4);
    } else if (i < n1 + n2 + n3 + n4) {
        int k = (i - n1 - n2 - n3) * 8;
        #pragma unroll
        for (int jj = 0; jj < 8; ++jj) {
            float2 cs; cs.x = fcos[k + jj]; cs.y = fsin[k + jj];
            csT[k + jj] = cs;                 // csT[t*32 + d2]
        }
    }
}

// ============ QKV GEMM with fused RoPE + scatter epilogue (R8-proven, BK=32) ============
__global__ __launch_bounds__(256) void k_gemm_qkv(const u16* __restrict__ A,
                                                  const u16* __restrict__ Bm,
                                                  u16* __restrict__ Qb,
                                                  u16* __restrict__ Kb,
                                                  u16* __restrict__ Vt,
                                                  const float2* __restrict__ csT) {
    __shared__ u16 As[128 * 32];
    __shared__ u16 Bs[128 * 32];
    const int K = CE;
    // XCD swizzle: 768 wgs, q=96 per XCD chunk
    const int c  = blockIdx.x + 24 * blockIdx.y;
    const int nc = (c & 7) * 96 + (c >> 3);
    const int m0 = (nc / 24) * 128;
    const int n0 = (nc % 24) * 128;

    const int tid  = threadIdx.x;
    const int w    = tid >> 6;
    const int lane = tid & 63;
    const int lr   = lane & 15, lg = lane >> 4;
    const int wm   = (w >> 1) * 64, wn = (w & 1) * 64;

    const int o0 = w * 2048 + lane * 16, o1 = o0 + 1024;
    const int ar0 = o0 >> 6, ar1 = o1 >> 6;
    const int ac0 = (o0 & 63) >> 1, ac1 = (o1 & 63) >> 1;
    const size_t aof0 = (size_t)(m0 + ar0) * K + ac0;
    const size_t aof1 = (size_t)(m0 + ar1) * K + ac1;
    const size_t bof0 = (size_t)(n0 + ar0) * K + ac0;
    const size_t bof1 = (size_t)(n0 + ar1) * K + ac1;
    u16* dA0 = &As[w * 1024];       u16* dA1 = &As[w * 1024 + 512];
    u16* dB0 = &Bs[w * 1024];       u16* dB1 = &Bs[w * 1024 + 512];

    f32x4 acc[4][4] = {};

    for (int k0 = 0; k0 < K; k0 += 32) {
        GLDS16(A  + aof0 + k0, dA0);
        GLDS16(A  + aof1 + k0, dA1);
        GLDS16(Bm + bof0 + k0, dB0);
        GLDS16(Bm + bof1 + k0, dB1);
        __syncthreads();
        s16x8 af[4], bf[4];
        #pragma unroll
        for (int i = 0; i < 4; ++i)
            af[i] = *reinterpret_cast<const s16x8*>(&As[(wm + i * 16 + lr) * 32 + lg * 8]);
        #pragma unroll
        for (int j = 0; j < 4; ++j)
            bf[j] = *reinterpret_cast<const s16x8*>(&Bs[(wn + j * 16 + lr) * 32 + lg * 8]);
        #pragma unroll
        for (int i = 0; i < 4; ++i)
            #pragma unroll
            for (int j = 0; j < 4; ++j)
                acc[i][j] = __builtin_amdgcn_mfma_f32_16x16x32_bf16(af[i], bf[j], acc[i][j], 0, 0, 0);
        __syncthreads();
    }

    // fused epilogue (lanes vary along d -> coalesced stores; RoPE pair via shfl_xor(1))
    const float QS = 0.18033688011112042f;   // (1/sqrt(64)) * log2(e)
    const int bb = m0 / TT;
    const int tb = m0 - bb * TT + wm;
    #pragma unroll
    for (int i = 0; i < 4; ++i) {
        const int t0 = tb + i * 16 + lg * 4;
        #pragma unroll
        for (int j = 0; j < 4; ++j) {
            const int n = n0 + wn + j * 16 + lr;
            if (n0 < NH * HD) {                      // ---- Q: RoPE + QS ----
                const int hh = n >> 6, d = n & 63;
                #pragma unroll
                for (int r = 0; r < 4; ++r) {
                    const int t = t0 + r;
                    const float2 cs = csT[t * 32 + (d >> 1)];
                    float v = acc[i][j][r];
                    float p = __shfl_xor(v, 1, 64);
                    float o = ((lr & 1) ? (p * cs.y + v * cs.x) : (v * cs.x - p * cs.y)) * QS;
                    float po = __shfl_xor(o, 1, 64);
                    if (!(lr & 1))
                        *reinterpret_cast<uint32_t*>(Qb + ((size_t)((bb * NH + hh) * TT + t)) * HD + d) = cvtpk(o, po);
                }
            } else if (n0 < (NH + NKV) * HD) {       // ---- K: RoPE ----
                const int fk = n - NH * HD;
                const int hh = fk >> 6, d = fk & 63;
                #pragma unroll
                for (int r = 0; r < 4; ++r) {
                    const int t = t0 + r;
                    const float2 cs = csT[t * 32 + (d >> 1)];
                    float v = acc[i][j][r];
                    float p = __shfl_xor(v, 1, 64);
                    float o = (lr & 1) ? (p * cs.y + v * cs.x) : (v * cs.x - p * cs.y);
                    float po = __shfl_xor(o, 1, 64);
                    if (!(lr & 1))
                        *reinterpret_cast<uint32_t*>(Kb + ((size_t)((bb * NKV + hh) * TT + t)) * HD + d) = cvtpk(o, po);
                }
            } else {                                  // ---- V: transpose store ----
                const int fv = n - (NH + NKV) * HD;
                const int vh = fv >> 6, d = fv & 63;
                uint2 st;
                st.x = cvtpk(acc[i][j][0], acc[i][j][1]);
                st.y = cvtpk(acc[i][j][2], acc[i][j][3]);
                *reinterpret_cast<uint2*>(Vt + ((size_t)(bb * NKV + vh) * HD + d) * TT + t0) = st;
            }
        }
    }
}

// ---------------- bf16 GEMM, f32 out (proj): C(M,N) = A(M,K) @ B(N,K)^T ----------------
__global__ __launch_bounds__(256) void k_gemm_bt(const u16* __restrict__ A,
                                                 const u16* __restrict__ Bm,
                                                 float* __restrict__ Cout,
                                                 int M, int N, int K) {
    __shared__ u16 As[128 * 32];
    __shared__ u16 Bs[128 * 32];
    // XCD swizzle: 512 wgs, q=64 per XCD chunk
    const int c  = blockIdx.x + 16 * blockIdx.y;
    const int nc = (c & 7) * 64 + (c >> 3);
    const int m0 = (nc >> 4) * 128;
    const int n0 = (nc & 15) * 128;

    const int tid  = threadIdx.x;
    const int w    = tid >> 6;
    const int lane = tid & 63;
    const int lr   = lane & 15, lg = lane >> 4;
    const int wm   = (w >> 1) * 64, wn = (w & 1) * 64;

    const int o0 = w * 2048 + lane * 16, o1 = o0 + 1024;
    const int ar0 = o0 >> 6, ar1 = o1 >> 6;
    const int ac0 = (o0 & 63) >> 1, ac1 = (o1 & 63) >> 1;
    const size_t aof0 = (size_t)(m0 + ar0) * K + ac0;
    const size_t aof1 = (size_t)(m0 + ar1) * K + ac1;
    const size_t bof0 = (size_t)(n0 + ar0) * K + ac0;
    const size_t bof1 = (size_t)(n0 + ar1) * K + ac1;
    u16* dA0 = &As[w * 1024];       u16* dA1 = &As[w * 1024 + 512];
    u16* dB0 = &Bs[w * 1024];       u16* dB1 = &Bs[w * 1024 + 512];

    f32x4 acc[4][4] = {};

    for (int k0 = 0; k0 < K; k0 += 32) {
        GLDS16(A  + aof0 + k0, dA0);
        GLDS16(A  + aof1 + k0, dA1);
        GLDS16(Bm + bof0 + k0, dB0);
        GLDS16(Bm + bof1 + k0, dB1);
        __syncthreads();
        s16x8 af[4], bf[4];
        #pragma unroll
        for (int i = 0; i < 4; ++i)
            af[i] = *reinterpret_cast<const s16x8*>(&As[(wm + i * 16 + lr) * 32 + lg * 8]);
        #pragma unroll
        for (int j = 0; j < 4; ++j)
            bf[j] = *reinterpret_cast<const s16x8*>(&Bs[(wn + j * 16 + lr) * 32 + lg * 8]);
        #pragma unroll
        for (int i = 0; i < 4; ++i)
            #pragma unroll
            for (int j = 0; j < 4; ++j)
                acc[i][j] = __builtin_amdgcn_mfma_f32_16x16x32_bf16(af[i], bf[j], acc[i][j], 0, 0, 0);
        __syncthreads();
    }

    #pragma unroll
    for (int i = 0; i < 4; ++i)
        #pragma unroll
        for (int j = 0; j < 4; ++j)
            #pragma unroll
            for (int r = 0; r < 4; ++r) {
                int m = m0 + wm + i * 16 + lg * 4 + r;
                int n = n0 + wn + j * 16 + lr;
                __builtin_nontemporal_store(acc[i][j][r], &Cout[(size_t)m * N + n]);
            }
}

// ---------------- causal GQA flash attention: 8-wave shared-KV, ADJACENT pairs ----
// grid (8, NH, B), 512 threads. KVH-XCD remap: linear block id -> (kvh=xcd, b, hr, u)
// so each XCD's L2 holds exactly two KV streams (1 MB of 4 MB). CU pairing (t, t+32)
// within an XCD puts (b=0,u) with (b=1,u) on one CU -> 36 tile rounds/CU, uniform.
// Waves 0-3 own q-tile j1=2m+1, waves 4-7 own j2=2m (~97% wave utilization).
// Per wave per tile: 1 K-GLDS16 + 1 V-GLDS16 (counted vmcnt(2)). Inner body: swapped
// QK^T 32x32, lane-local defer-max softmax, in-register P via cvt_pk+permlane32_swap.
__global__ __launch_bounds__(512) void k_attn(const u16* __restrict__ Q,
                                              const u16* __restrict__ Kb,
                                              const u16* __restrict__ Vt,
                                              u16* __restrict__ Y) {
    __shared__ u16 Ks[2][4096];      // [kv 64][d 64] swizzled (8KB per buf)
    __shared__ u16 Vs[2][4096];      // [d 64][kv 64] swizzled

    const int tid = threadIdx.x;
    const int w = tid >> 6, lane = tid & 63;
    const int wv = w & 3, half = w >> 2;
    const int ql = lane & 31, hi = lane >> 5;
    const int hi16 = hi << 4;

    // KVH-XCD block remap: lid = xcd + 8*(b*32 + hr*8 + u)
    const int lid = (int)blockIdx.x + 8 * (int)blockIdx.y + 8 * NH * (int)blockIdx.z;
    const int kvh = lid & 7;             // = XCD under mod-8 dispatch
    const int q8  = lid >> 3;            // 0..63
    const int b   = q8 >> 5;
    const int s   = q8 & 31;
    const int hr  = s >> 3;
    const int u   = s & 7;
    const int h   = kvh * 4 + hr;

    const int m  = b ? (7 - u) : u;
    const int j1 = 2 * m + 1, j2 = 2 * m;
    const int jq = half ? j2 : j1;
    const int q0w  = jq * 128 + wv * 32;
    const int nt   = 2 * j1 + 2;         // block loop length (= 4m+4)
    const int tmxw = (q0w + 31) >> 6;    // wave's diagonal tile index
    const int qabs = q0w + ql;           // this lane's q row

    const u16* qbase = Q  + ((size_t)(b * NH  + h  ) * TT) * HD;
    const u16* kbase = Kb + ((size_t)(b * NKV + kvh) * TT) * HD;
    const u16* vbase = Vt + ((size_t)(b * NKV + kvh) * HD) * TT;

    // staging: wave w covers bytes [w*1024, w*1024+1024) of each 8KB buffer
    const int o0 = w * 1024 + lane * 16;
    const int r0 = o0 >> 7;
    const int c0 = (o0 & 127) ^ ((r0 & 7) << 4);
    const size_t kof0 = (size_t)r0 * HD + (c0 >> 1);
    const size_t vof0 = (size_t)r0 * TT + (c0 >> 1);

    // per-lane read-address constants
    const char* KsB = (const char*)&Ks[0][0];
    const char* VsB = (const char*)&Vs[0][0];
    const int krb0 = (0 * 32 + ql) * 128, ksz0 = ((0 * 32 + ql) & 7) << 4;
    const int krb1 = (1 * 32 + ql) * 128, ksz1 = ((1 * 32 + ql) & 7) << 4;

    // Q B-frags (d-slices of 16)
    s16x8 qf[4];
    #pragma unroll
    for (int ds = 0; ds < 4; ++ds)
        qf[ds] = *reinterpret_cast<const s16x8*>(qbase + (size_t)qabs * HD + ds * 16 + 8 * hi);
    asm volatile("s_waitcnt vmcnt(0)" ::: "memory");   // only stage loads counted after this

    GLDS16(kbase + kof0, &Ks[0][w * 512]);
    GLDS16(vbase + vof0, &Vs[0][w * 512]);

    float mrow = -1e30f, lrowp = 0.f;
    f32x16 oT0 = {}, oT1 = {};           // O^T accumulators, d-tiles 0/1

    for (int t = 0; t < nt; ++t) {
        const int cur = t & 1;
        const int kv0 = t * 64;
        if (t + 1 < nt) {
            GLDS16(kbase + (size_t)(kv0 + 64) * HD + kof0, &Ks[cur ^ 1][w * 512]);
            GLDS16(vbase + (kv0 + 64) + vof0, &Vs[cur ^ 1][w * 512]);
            asm volatile("s_waitcnt vmcnt(2)" ::: "memory");   // tile t resident, t+1 in flight
        } else {
            asm volatile("s_waitcnt vmcnt(0)" ::: "memory");
        }
        __builtin_amdgcn_s_barrier();
        __builtin_amdgcn_sched_barrier(0);

        if (t <= tmxw) {                 // wave-uniform causal skip
            const int bufo = cur * 8192;

            // S^T = K . Q^T  (two 32-kv sub-tiles)
            f32x16 sc0 = {}, sc1 = {};
            __builtin_amdgcn_s_setprio(1);
            #pragma unroll
            for (int ds = 0; ds < 4; ++ds) {
                s16x8 k0 = *reinterpret_cast<const s16x8*>(KsB + bufo + krb0 + (((ds << 5) | hi16) ^ ksz0));
                s16x8 k1 = *reinterpret_cast<const s16x8*>(KsB + bufo + krb1 + (((ds << 5) | hi16) ^ ksz1));
                sc0 = __builtin_amdgcn_mfma_f32_32x32x16_bf16(k0, qf[ds], sc0, 0, 0, 0);
                sc1 = __builtin_amdgcn_mfma_f32_32x32x16_bf16(k1, qf[ds], sc1, 0, 0, 0);
            }
            __builtin_amdgcn_s_setprio(0);

            float p0[16], p1[16];
            #pragma unroll
            for (int r = 0; r < 16; ++r) { p0[r] = sc0[r]; p1[r] = sc1[r]; }

            if (t == tmxw) {             // mask only the diagonal tile
                const int dq = qabs - kv0 - 4 * hi;
                #pragma unroll
                for (int r = 0; r < 16; ++r) {
                    const int kr = (r & 3) + 8 * (r >> 2);
                    p0[r] = (kr      <= dq) ? p0[r] : -1e30f;
                    p1[r] = (kr + 32 <= dq) ? p1[r] : -1e30f;
                }
            }

            // defer-max: lane-local check, rare rescale
            float tmax = fmaxf(p0[0], p1[0]);
            #pragma unroll
            for (int r = 1; r < 16; ++r) tmax = fmaxf(fmaxf(tmax, p0[r]), p1[r]);
            if (__any(tmax > mrow + 8.f)) {
                float tf = fmaxf(tmax, __shfl_xor(tmax, 32, 64));
                float mn = fmaxf(mrow, tf);
                float alpha = __builtin_amdgcn_exp2f(mrow - mn);
                mrow = mn;
                lrowp *= alpha;
                #pragma unroll
                for (int r = 0; r < 16; ++r) { oT0[r] *= alpha; oT1[r] *= alpha; }
            }

            float sum = 0.f;
            #pragma unroll
            for (int r = 0; r < 16; ++r) {
                p0[r] = __builtin_amdgcn_exp2f(p0[r] - mrow);
                p1[r] = __builtin_amdgcn_exp2f(p1[r] - mrow);
                sum += p0[r] + p1[r];
            }
            lrowp += sum;

            __builtin_amdgcn_s_setprio(1);
            // PV: kt=0 sub-tile (P from p0)
            #pragma unroll
            for (int ks = 0; ks < 2; ++ks) {
                uint32_t a0 = cvtpk(p0[ks * 8 + 0], p0[ks * 8 + 1]);
                uint32_t b0 = cvtpk(p0[ks * 8 + 4], p0[ks * 8 + 5]);
                plswap(a0, b0);
                uint32_t a1 = cvtpk(p0[ks * 8 + 2], p0[ks * 8 + 3]);
                uint32_t b1 = cvtpk(p0[ks * 8 + 6], p0[ks * 8 + 7]);
                plswap(a1, b1);
                union { uint32_t d[4]; s16x8 v; } pb;
                pb.d[0] = a0; pb.d[1] = a1; pb.d[2] = b0; pb.d[3] = b1;
                const int colb = (0 << 6) | (ks << 5) | hi16;
                s16x8 v0 = *reinterpret_cast<const s16x8*>(VsB + bufo + krb0 + (colb ^ ksz0));
                s16x8 v1 = *reinterpret_cast<const s16x8*>(VsB + bufo + krb1 + (colb ^ ksz1));
                oT0 = __builtin_amdgcn_mfma_f32_32x32x16_bf16(v0, pb.v, oT0, 0, 0, 0);
                oT1 = __builtin_amdgcn_mfma_f32_32x32x16_bf16(v1, pb.v, oT1, 0, 0, 0);
            }
            // PV: kt=1 sub-tile (P from p1)
            #pragma unroll
            for (int ks = 0; ks < 2; ++ks) {
                uint32_t a0 = cvtpk(p1[ks * 8 + 0], p1[ks * 8 + 1]);
                uint32_t b0 = cvtpk(p1[ks * 8 + 4], p1[ks * 8 + 5]);
                plswap(a0, b0);
                uint32_t a1 = cvtpk(p1[ks * 8 + 2], p1[ks * 8 + 3]);
                uint32_t b1 = cvtpk(p1[ks * 8 + 6], p1[ks * 8 + 7]);
                plswap(a1, b1);
                union { uint32_t d[4]; s16x8 v; } pb;
                pb.d[0] = a0; pb.d[1] = a1; pb.d[2] = b0; pb.d[3] = b1;
                const int colb = (1 << 6) | (ks << 5) | hi16;
                s16x8 v0 = *reinterpret_cast<const s16x8*>(VsB + bufo + krb0 + (colb ^ ksz0));
                s16x8 v1 = *reinterpret_cast<const s16x8*>(VsB + bufo + krb1 + (colb ^ ksz1));
                oT0 = __builtin_amdgcn_mfma_f32_32x32x16_bf16(v0, pb.v, oT0, 0, 0, 0);
                oT1 = __builtin_amdgcn_mfma_f32_32x32x16_bf16(v1, pb.v, oT1, 0, 0, 0);
            }
            __builtin_amdgcn_s_setprio(0);
        }

        __builtin_amdgcn_sched_barrier(0);
        __builtin_amdgcn_s_barrier();
    }

    // epilogue: combine lane-pair partial sums, normalize, write O^T -> Y rows
    lrowp += __shfl_xor(lrowp, 32, 64);
    const float rinv = 1.f / lrowp;
    const size_t yrow = ((size_t)(b * TT + qabs) * NH + h) * HD;
    #pragma unroll
    for (int rp = 0; rp < 8; ++rp) {
        const int d = ((2 * rp) & 3) + 8 * (rp >> 1) + 4 * hi;
        *reinterpret_cast<uint32_t*>(Y + yrow + d) =
            cvtpk(oT0[2 * rp] * rinv, oT0[2 * rp + 1] * rinv);
        *reinterpret_cast<uint32_t*>(Y + yrow + 32 + d) =
            cvtpk(oT1[2 * rp] * rinv, oT1[2 * rp + 1] * rinv);
    }
}

// ---------------- launch ----------------
extern "C" void kernel_launch(void* const* d_in, const int* in_sizes, int n_in,
                              void* d_out, int out_size, void* d_ws, size_t ws_size,
                              hipStream_t stream) {
    (void)in_sizes; (void)n_in; (void)out_size; (void)ws_size;
    const float* x     = (const float*)d_in[0];
    const float* wqkv  = (const float*)d_in[1];
    const float* wproj = (const float*)d_in[2];
    const float* fcos  = (const float*)d_in[3];
    const float* fsin  = (const float*)d_in[4];

    char* ws = (char*)d_ws;
    size_t off = 0;
    auto alloc = [&](size_t bytes) { void* p = ws + off; off += (bytes + 255) & ~(size_t)255; return p; };
    u16*    Xbf  = (u16*)alloc((size_t)MM * CE * 2);
    u16*    Wqb  = (u16*)alloc((size_t)QKVD * CE * 2);
    u16*    Wpb  = (u16*)alloc((size_t)CE * CE * 2);
    u16*    Qb   = (u16*)alloc((size_t)BB * NH * TT * HD * 2);
    u16*    Kbuf = (u16*)alloc((size_t)BB * NKV * TT * HD * 2);
    u16*    Vtb  = (u16*)alloc((size_t)BB * NKV * HD * TT * 2);
    u16*    Yb   = (u16*)alloc((size_t)MM * CE * 2);
    float2* csT  = (float2*)alloc((size_t)32 * TT * sizeof(float2));

    const int ncvt = MM * CE / 8 + QKVD * CE / 8 + CE * CE / 8 + 32 * TT / 8;
    k_cvt_all<<<(ncvt + 255) / 256, 256, 0, stream>>>(x, wqkv, wproj,
                                                      (uint32_t*)Xbf, (uint32_t*)Wqb, (uint32_t*)Wpb,
                                                      fcos, fsin, csT);

    dim3 g1(QKVD / 128, MM / 128);
    k_gemm_qkv<<<g1, 256, 0, stream>>>(Xbf, Wqb, Qb, Kbuf, Vtb, csT);

    dim3 ga(8, NH, BB);
    k_attn<<<ga, 512, 0, stream>>>(Qb, Kbuf, Vtb, Yb);

    dim3 g2(CE / 128, MM / 128);
    k_gemm_bt<<<g2, 256, 0, stream>>>(Yb, Wpb, (float*)d_out, MM, CE, CE);
}